// Round 3
// baseline (254.521 us; speedup 1.0000x reference)
//
#include <hip/hip_runtime.h>

#define T_ 4
#define B_ 32
#define C_ 384
#define N_ 256
#define HEADS_ 8
#define DH_ 48
#define EPS_ 1e-5f
#define NW_ (C_*C_)

typedef _Float16 f16;
typedef __attribute__((ext_vector_type(8))) _Float16 f16x8;
typedef __attribute__((ext_vector_type(16))) float f32x16;

#define PSCALE     4096.0f
#define PSCALE_INV (1.0f/4096.0f)

// ---------------------------------------------------------------------------
// Kernel 1: combined input-LIF+transpose (z<32) and weight-split (z==32).
// lif part: spikes s[t][b][n][c] (f16 0/1), LDS transpose per t.
// wsplit part: w = p0 + p1/4096 f16 plane pairs for q,k,proj weights.
// ---------------------------------------------------------------------------
__global__ __launch_bounds__(256)
void prep_kernel(const float* __restrict__ x, f16* __restrict__ s,
                 const float* __restrict__ qw, const float* __restrict__ kw,
                 const float* __restrict__ pw,
                 f16* __restrict__ q2, f16* __restrict__ k2, f16* __restrict__ p2)
{
    __shared__ f16 Ls[64][72];
    if (blockIdx.z == 32) {
        // weight split: 24 xy-blocks * 256 threads, 24 elems each = 147456
        int idx = (blockIdx.y * 4 + blockIdx.x) * 256 + threadIdx.x;
#pragma unroll
        for (int it = 0; it < 24; ++it) {
            {
                float w = qw[idx]; f16 a = (f16)w; f16 bb = (f16)((w - (float)a) * PSCALE);
                q2[idx] = a; q2[NW_ + idx] = bb;
            }
            {
                float w = kw[idx]; f16 a = (f16)w; f16 bb = (f16)((w - (float)a) * PSCALE);
                k2[idx] = a; k2[NW_ + idx] = bb;
            }
            {
                float w = pw[idx]; f16 a = (f16)w; f16 bb = (f16)((w - (float)a) * PSCALE);
                p2[idx] = a; p2[NW_ + idx] = bb;
            }
            idx += 6144;
        }
        return;
    }

    const int tid = threadIdx.x;
    const int n0 = blockIdx.x * 64;
    const int c0 = blockIdx.y * 64;
    const int b  = blockIdx.z;
    const int cl = tid >> 4;        // 0..15
    const int nl = (tid & 15) * 4;  // 0..60

    float v[4][4];
#pragma unroll
    for (int i = 0; i < 4; ++i)
#pragma unroll
        for (int j = 0; j < 4; ++j) v[i][j] = 0.f;

    for (int t = 0; t < T_; ++t) {
        const float* xt = x + (((size_t)t * B_ + b) * C_) * N_;
#pragma unroll
        for (int i = 0; i < 4; ++i) {
            int c = c0 + cl + 16 * i;
            float4 xv = *(const float4*)&xt[(size_t)c * N_ + n0 + nl];
            float xa[4] = {xv.x, xv.y, xv.z, xv.w};
#pragma unroll
            for (int j = 0; j < 4; ++j) {
                float vv = 0.5f * v[i][j] + xa[j];
                int sp = (vv >= 1.0f) ? 1 : 0;
                v[i][j] = sp ? 0.f : vv;
                Ls[nl + j][cl + 16 * i] = sp ? (f16)1.0f : (f16)0.0f;
            }
        }
        __syncthreads();
        {
            int r = tid >> 2, ch = (tid & 3) * 16;
            uint4 w0 = *(const uint4*)&Ls[r][ch];
            uint4 w1 = *(const uint4*)&Ls[r][ch + 8];
            f16* dst = s + (((size_t)t * B_ + b) * N_ + n0 + r) * (size_t)C_ + c0 + ch;
            *(uint4*)dst = w0;
            *(uint4*)(dst + 8) = w1;
        }
        __syncthreads();
    }
}

// ---------------------------------------------------------------------------
// Kernel 2: FUSED q+k GEMM + BN + LIF. Path-per-wave: wave0=q, wave1=k share
// the A (spike) tile. Block tile 64n x 32d, 2 waves, wave tile 64n x 32d
// (2 n-subtiles of 32). Dual f16 planes, dual accumulators. Grid (4,12,32).
// ---------------------------------------------------------------------------
__global__ __launch_bounds__(128, 2)
void qk_fused_kernel(const f16* __restrict__ Wq, const f16* __restrict__ Wk,
                     const f16* __restrict__ S,
                     const float* __restrict__ qg, const float* __restrict__ qb,
                     const float* __restrict__ qm, const float* __restrict__ qv,
                     const float* __restrict__ kg, const float* __restrict__ kb,
                     const float* __restrict__ km, const float* __restrict__ kv,
                     f16* __restrict__ q_spk, f16* __restrict__ k_spk)
{
    __shared__ f16 As[64][72];       // [n][c]
    __shared__ f16 Bs[4][32][72];    // [plane(q0,q1,k0,k1)][d][c]

    const int tid  = threadIdx.x;
    const int lane = tid & 63;
    const int wave = tid >> 6;       // 0 = q path, 1 = k path
    const int l31  = lane & 31;
    const int lhi  = lane >> 5;
    const int n0 = blockIdx.x * 64;
    const int d0 = blockIdx.y * 32;
    const int b  = blockIdx.z;
    const int dcol = d0 + l31;

    const float* g_  = wave ? kg : qg;
    const float* be_ = wave ? kb : qb;
    const float* m_  = wave ? km : qm;
    const float* va_ = wave ? kv : qv;
    f16* spk = wave ? k_spk : q_spk;

    const float inv = g_[dcol] / sqrtf(va_[dcol] + EPS_);
    const float add = be_[dcol] - m_[dcol] * inv;

    // staging assignments (128 threads)
    const int ar = tid >> 1;          // A row 0..63
    const int ac = (tid & 1) * 32;    // A col half (halves)
    const int br = tid >> 2;          // B row 0..31
    const int bc = (tid & 3) * 16;    // B col quarter (halves)

    const f16* Bsrc0 = Wq;
    const f16* Bsrc1 = Wq + NW_;
    const f16* Bsrc2 = Wk;
    const f16* Bsrc3 = Wk + NW_;

    float v[32];
#pragma unroll
    for (int r = 0; r < 32; ++r) v[r] = 0.f;

    for (int t = 0; t < T_; ++t) {
        const f16* St = S + ((size_t)(t * B_ + b) * N_) * (size_t)C_;
        f32x16 acc0[2], acc1[2];
#pragma unroll
        for (int s2 = 0; s2 < 2; ++s2)
#pragma unroll
            for (int r = 0; r < 16; ++r) { acc0[s2][r] = 0.f; acc1[s2][r] = 0.f; }

        for (int kc = 0; kc < C_; kc += 64) {
            __syncthreads();
            const f16* ga = St + (size_t)(n0 + ar) * C_ + kc + ac;
            *(uint4*)&As[ar][ac]      = *(const uint4*)(ga);
            *(uint4*)&As[ar][ac + 8]  = *(const uint4*)(ga + 8);
            *(uint4*)&As[ar][ac + 16] = *(const uint4*)(ga + 16);
            *(uint4*)&As[ar][ac + 24] = *(const uint4*)(ga + 24);
            {
                size_t wo = (size_t)(d0 + br) * C_ + kc + bc;
                *(uint4*)&Bs[0][br][bc]     = *(const uint4*)(Bsrc0 + wo);
                *(uint4*)&Bs[0][br][bc + 8] = *(const uint4*)(Bsrc0 + wo + 8);
                *(uint4*)&Bs[1][br][bc]     = *(const uint4*)(Bsrc1 + wo);
                *(uint4*)&Bs[1][br][bc + 8] = *(const uint4*)(Bsrc1 + wo + 8);
                *(uint4*)&Bs[2][br][bc]     = *(const uint4*)(Bsrc2 + wo);
                *(uint4*)&Bs[2][br][bc + 8] = *(const uint4*)(Bsrc2 + wo + 8);
                *(uint4*)&Bs[3][br][bc]     = *(const uint4*)(Bsrc3 + wo);
                *(uint4*)&Bs[3][br][bc + 8] = *(const uint4*)(Bsrc3 + wo + 8);
            }
            __syncthreads();
#pragma unroll
            for (int kk = 0; kk < 4; ++kk) {
                const int ko = kk * 16 + lhi * 8;
                f16x8 a0 = *(const f16x8*)&As[l31][ko];
                f16x8 a1 = *(const f16x8*)&As[32 + l31][ko];
                f16x8 b0 = *(const f16x8*)&Bs[2 * wave][l31][ko];
                f16x8 b1 = *(const f16x8*)&Bs[2 * wave + 1][l31][ko];
                acc0[0] = __builtin_amdgcn_mfma_f32_32x32x16_f16(a0, b0, acc0[0], 0, 0, 0);
                acc0[1] = __builtin_amdgcn_mfma_f32_32x32x16_f16(a1, b0, acc0[1], 0, 0, 0);
                acc1[0] = __builtin_amdgcn_mfma_f32_32x32x16_f16(a0, b1, acc1[0], 0, 0, 0);
                acc1[1] = __builtin_amdgcn_mfma_f32_32x32x16_f16(a1, b1, acc1[1], 0, 0, 0);
            }
        }
        // epilogue: combine planes -> BN -> LIF -> spike store (transposed)
        f16* spt = spk + ((size_t)(t * B_ + b) * N_) * (size_t)C_;
#pragma unroll
        for (int s2 = 0; s2 < 2; ++s2)
#pragma unroll
        for (int r = 0; r < 16; ++r) {
            int nrow = n0 + s2 * 32 + (r & 3) + 8 * (r >> 2) + 4 * lhi;
            float val = acc0[s2][r] + acc1[s2][r] * PSCALE_INV;
            float bnv = val * inv + add;
            float vv = 0.5f * v[s2 * 16 + r] + bnv;
            int sp = (vv >= 1.0f) ? 1 : 0;
            v[s2 * 16 + r] = sp ? 0.f : vv;
            spt[(size_t)nrow * C_ + dcol] = sp ? (f16)1.0f : (f16)0.0f;
        }
    }
}

// ---------------------------------------------------------------------------
// Kernel 3: fused head-sum + decayed memory + attention LIF.
// One thread per (b,h,n); loops t, counting 48 q-spikes (popcount of bit 10
// of f16 1.0=0x3C00) then runs the memory/LIF recurrences. No Sq tensor.
// ---------------------------------------------------------------------------
__global__ __launch_bounds__(256)
void head_attn_kernel(const f16* __restrict__ q_spk,
                      const float* __restrict__ alpha_p,
                      unsigned char* __restrict__ attn)
{
    int i = blockIdx.x * 256 + threadIdx.x;   // B*H*N = 65536
    int n = i & (N_ - 1);
    int h = (i >> 8) & (HEADS_ - 1);
    int b = i >> 11;
    const float alpha = alpha_p[0];
    const int stride = B_ * HEADS_ * N_;
    float M = 0.f, v = 0.f, Sprev = 0.f;
#pragma unroll
    for (int t = 0; t < T_; ++t) {
        const uint4* p = (const uint4*)(q_spk + (((size_t)(t * B_ + b) * N_) + n) * C_ + h * DH_);
        int cnt = 0;
#pragma unroll
        for (int j = 0; j < 6; ++j) {
            uint4 w = p[j];
            cnt += __popc(w.x & 0x04000400u) + __popc(w.y & 0x04000400u)
                 + __popc(w.z & 0x04000400u) + __popc(w.w & 0x04000400u);
        }
        float Sqt = (float)cnt;
        if (t == 0) M = Sqt;
        else        M = alpha * M + (1.f - alpha) * Sprev;
        float qsum = M + Sqt;
        float vv = 0.5f * v + qsum;
        unsigned char sp = (vv >= 0.5f) ? 1 : 0;
        v = sp ? 0.f : vv;
        attn[(size_t)t * stride + i] = sp;
        Sprev = Sqt;
    }
}

// ---------------------------------------------------------------------------
// Kernel 4: proj GEMM. Block 128n x 64d, 2 waves, wave tile 64n x 64d
// (0.75 LDS reads/MFMA). A = (attn & k_spk) masked at staging. Grid (2,6,128).
// ---------------------------------------------------------------------------
__global__ __launch_bounds__(128, 2)
void proj_gemm_kernel(const f16* __restrict__ Wp,   // [2][C][C]
                      const f16* __restrict__ K,    // [T][B][N][C]
                      const unsigned char* __restrict__ attn, // [T][B][H][N]
                      const float* __restrict__ bias,
                      const float* __restrict__ gamma, const float* __restrict__ beta,
                      const float* __restrict__ mean,  const float* __restrict__ var,
                      float* __restrict__ out)      // [T][B][C][N]
{
    __shared__ f16 As[128][72];
    __shared__ f16 Bs[2][64][72];

    const int tid  = threadIdx.x;
    const int lane = tid & 63;
    const int wave = tid >> 6;       // n-half
    const int l31  = lane & 31;
    const int lhi  = lane >> 5;
    const int n0 = blockIdx.x * 128;
    const int d0 = blockIdx.y * 64;
    const int tb = blockIdx.z;

    float inv[2], add[2];
#pragma unroll
    for (int u = 0; u < 2; ++u) {
        int d = d0 + u * 32 + l31;
        float iv = gamma[d] / sqrtf(var[d] + EPS_);
        inv[u] = iv;
        add[u] = beta[d] - mean[d] * iv + bias[d] * iv;
    }

    const f16* Kt = K + (size_t)tb * N_ * C_;
    const unsigned char* At = attn + (size_t)tb * HEADS_ * N_;

    const int brow = tid >> 1;          // 0..63
    const int bcol = (tid & 1) * 32;    // halves

    f32x16 acc[2][2][2];                // [s][u][plane]
#pragma unroll
    for (int s2 = 0; s2 < 2; ++s2)
#pragma unroll
        for (int u = 0; u < 2; ++u)
#pragma unroll
            for (int p = 0; p < 2; ++p)
#pragma unroll
                for (int r = 0; r < 16; ++r) acc[s2][u][p][r] = 0.f;

    for (int kc = 0; kc < C_; kc += 64) {
        __syncthreads();
        // A: one row per thread, mask per 16B chunk (48 % 8 == 0 keeps chunks in-head)
        {
            int nn = n0 + tid;
            const f16* ga = Kt + (size_t)nn * C_ + kc;
#pragma unroll
            for (int j = 0; j < 8; ++j) {
                int c = kc + 8 * j;
                int h = c / DH_;
                unsigned char am = At[(size_t)h * N_ + nn];
                uint4 val = am ? *(const uint4*)(ga + 8 * j) : make_uint4(0u, 0u, 0u, 0u);
                *(uint4*)&As[tid][8 * j] = val;
            }
        }
        {
            size_t wo = (size_t)(d0 + brow) * C_ + kc + bcol;
            *(uint4*)&Bs[0][brow][bcol]      = *(const uint4*)(Wp + wo);
            *(uint4*)&Bs[0][brow][bcol + 8]  = *(const uint4*)(Wp + wo + 8);
            *(uint4*)&Bs[0][brow][bcol + 16] = *(const uint4*)(Wp + wo + 16);
            *(uint4*)&Bs[0][brow][bcol + 24] = *(const uint4*)(Wp + wo + 24);
            *(uint4*)&Bs[1][brow][bcol]      = *(const uint4*)(Wp + NW_ + wo);
            *(uint4*)&Bs[1][brow][bcol + 8]  = *(const uint4*)(Wp + NW_ + wo + 8);
            *(uint4*)&Bs[1][brow][bcol + 16] = *(const uint4*)(Wp + NW_ + wo + 16);
            *(uint4*)&Bs[1][brow][bcol + 24] = *(const uint4*)(Wp + NW_ + wo + 24);
        }
        __syncthreads();
#pragma unroll
        for (int kk = 0; kk < 4; ++kk) {
            const int ko = kk * 16 + lhi * 8;
            f16x8 a0  = *(const f16x8*)&As[wave * 64 + l31][ko];
            f16x8 a1  = *(const f16x8*)&As[wave * 64 + 32 + l31][ko];
            f16x8 b00 = *(const f16x8*)&Bs[0][l31][ko];
            f16x8 b01 = *(const f16x8*)&Bs[0][32 + l31][ko];
            f16x8 b10 = *(const f16x8*)&Bs[1][l31][ko];
            f16x8 b11 = *(const f16x8*)&Bs[1][32 + l31][ko];
            acc[0][0][0] = __builtin_amdgcn_mfma_f32_32x32x16_f16(a0, b00, acc[0][0][0], 0, 0, 0);
            acc[0][1][0] = __builtin_amdgcn_mfma_f32_32x32x16_f16(a0, b01, acc[0][1][0], 0, 0, 0);
            acc[1][0][0] = __builtin_amdgcn_mfma_f32_32x32x16_f16(a1, b00, acc[1][0][0], 0, 0, 0);
            acc[1][1][0] = __builtin_amdgcn_mfma_f32_32x32x16_f16(a1, b01, acc[1][1][0], 0, 0, 0);
            acc[0][0][1] = __builtin_amdgcn_mfma_f32_32x32x16_f16(a0, b10, acc[0][0][1], 0, 0, 0);
            acc[0][1][1] = __builtin_amdgcn_mfma_f32_32x32x16_f16(a0, b11, acc[0][1][1], 0, 0, 0);
            acc[1][0][1] = __builtin_amdgcn_mfma_f32_32x32x16_f16(a1, b10, acc[1][0][1], 0, 0, 0);
            acc[1][1][1] = __builtin_amdgcn_mfma_f32_32x32x16_f16(a1, b11, acc[1][1][1], 0, 0, 0);
        }
    }
    // epilogue: combine planes -> bias+BN -> float4 stores along n
#pragma unroll
    for (int s2 = 0; s2 < 2; ++s2)
#pragma unroll
    for (int u = 0; u < 2; ++u) {
        int dcol = d0 + u * 32 + l31;
        float* orow = out + ((size_t)tb * C_ + dcol) * N_ + n0 + wave * 64 + s2 * 32 + 4 * lhi;
#pragma unroll
        for (int g = 0; g < 4; ++g) {
            float4 o;
            o.x = (acc[s2][u][0][g * 4 + 0] + acc[s2][u][1][g * 4 + 0] * PSCALE_INV) * inv[u] + add[u];
            o.y = (acc[s2][u][0][g * 4 + 1] + acc[s2][u][1][g * 4 + 1] * PSCALE_INV) * inv[u] + add[u];
            o.z = (acc[s2][u][0][g * 4 + 2] + acc[s2][u][1][g * 4 + 2] * PSCALE_INV) * inv[u] + add[u];
            o.w = (acc[s2][u][0][g * 4 + 3] + acc[s2][u][1][g * 4 + 3] * PSCALE_INV) * inv[u] + add[u];
            *(float4*)&orow[8 * g] = o;
        }
    }
}

// ---------------------------------------------------------------------------
extern "C" void kernel_launch(void* const* d_in, const int* in_sizes, int n_in,
                              void* d_out, int out_size, void* d_ws, size_t ws_size,
                              hipStream_t stream)
{
    const float* x       = (const float*)d_in[0];
    const float* q_w     = (const float*)d_in[1];
    const float* q_gamma = (const float*)d_in[2];
    const float* q_beta  = (const float*)d_in[3];
    const float* q_mean  = (const float*)d_in[4];
    const float* q_var   = (const float*)d_in[5];
    const float* k_w     = (const float*)d_in[6];
    const float* k_gamma = (const float*)d_in[7];
    const float* k_beta  = (const float*)d_in[8];
    const float* k_mean  = (const float*)d_in[9];
    const float* k_var   = (const float*)d_in[10];
    const float* proj_w  = (const float*)d_in[11];
    const float* proj_b  = (const float*)d_in[12];
    const float* p_gamma = (const float*)d_in[13];
    const float* p_beta  = (const float*)d_in[14];
    const float* p_mean  = (const float*)d_in[15];
    const float* p_var   = (const float*)d_in[16];
    const float* m_alpha = (const float*)d_in[17];

    float* out = (float*)d_out;

    const size_t SPK_BYTES = (size_t)T_ * B_ * N_ * C_ * sizeof(f16); // 25,165,824
    const size_t W2_BYTES  = (size_t)2 * NW_ * sizeof(f16);           // 589,824

    unsigned char* ws = (unsigned char*)d_ws;
    size_t off = 0;
    auto carve = [&](size_t bytes) {
        off = (off + 255) & ~(size_t)255;
        void* p = ws + off;
        off += bytes;
        return p;
    };
    f16* s_f16  = (f16*)carve(SPK_BYTES);
    f16* q_spk  = (f16*)carve(SPK_BYTES);
    f16* k_spk  = (f16*)carve(SPK_BYTES);
    f16* Wq2    = (f16*)carve(W2_BYTES);
    f16* Wk2    = (f16*)carve(W2_BYTES);
    f16* Wp2    = (f16*)carve(W2_BYTES);
    unsigned char* attn = (unsigned char*)carve((size_t)T_ * B_ * HEADS_ * N_);

    // 1. input LIF + transpose (z<32) and weight split (z==32)
    dim3 pgrid1(4, 6, 33);
    prep_kernel<<<pgrid1, 256, 0, stream>>>(x, s_f16, q_w, k_w, proj_w, Wq2, Wk2, Wp2);

    // 2. fused q+k GEMM + BN + LIF
    dim3 qkgrid(N_ / 64, C_ / 32, B_);
    qk_fused_kernel<<<qkgrid, 128, 0, stream>>>(Wq2, Wk2, s_f16,
                                                q_gamma, q_beta, q_mean, q_var,
                                                k_gamma, k_beta, k_mean, k_var,
                                                q_spk, k_spk);

    // 3. fused head-sum + memory + attn LIF
    head_attn_kernel<<<(B_ * HEADS_ * N_) / 256, 256, 0, stream>>>(q_spk, m_alpha, attn);

    // 4. proj GEMM -> out
    dim3 pjgrid(N_ / 128, C_ / 64, T_ * B_);
    proj_gemm_kernel<<<pjgrid, 128, 0, stream>>>(Wp2, k_spk, attn, proj_b,
                                                 p_gamma, p_beta, p_mean, p_var, out);
}

// Round 4
// 230.720 us; speedup vs baseline: 1.1032x; 1.1032x over previous
//
#include <hip/hip_runtime.h>

#define T_ 4
#define B_ 32
#define C_ 384
#define N_ 256
#define HEADS_ 8
#define DH_ 48
#define EPS_ 1e-5f
#define NW_ (C_*C_)

typedef _Float16 f16;
typedef __attribute__((ext_vector_type(8))) _Float16 f16x8;
typedef __attribute__((ext_vector_type(16))) float f32x16;

#define PSCALE     4096.0f
#define PSCALE_INV (1.0f/4096.0f)

// ---------------------------------------------------------------------------
// Kernel 1: combined input-LIF+transpose (z<32) and weight-split (z==32).
// ---------------------------------------------------------------------------
__global__ __launch_bounds__(256)
void prep_kernel(const float* __restrict__ x, f16* __restrict__ s,
                 const float* __restrict__ qw, const float* __restrict__ kw,
                 const float* __restrict__ pw,
                 f16* __restrict__ q2, f16* __restrict__ k2, f16* __restrict__ p2)
{
    __shared__ f16 Ls[64][72];
    if (blockIdx.z == 32) {
        int idx = (blockIdx.y * 4 + blockIdx.x) * 256 + threadIdx.x;
#pragma unroll
        for (int it = 0; it < 24; ++it) {
            {
                float w = qw[idx]; f16 a = (f16)w; f16 bb = (f16)((w - (float)a) * PSCALE);
                q2[idx] = a; q2[NW_ + idx] = bb;
            }
            {
                float w = kw[idx]; f16 a = (f16)w; f16 bb = (f16)((w - (float)a) * PSCALE);
                k2[idx] = a; k2[NW_ + idx] = bb;
            }
            {
                float w = pw[idx]; f16 a = (f16)w; f16 bb = (f16)((w - (float)a) * PSCALE);
                p2[idx] = a; p2[NW_ + idx] = bb;
            }
            idx += 6144;
        }
        return;
    }

    const int tid = threadIdx.x;
    const int n0 = blockIdx.x * 64;
    const int c0 = blockIdx.y * 64;
    const int b  = blockIdx.z;
    const int cl = tid >> 4;
    const int nl = (tid & 15) * 4;

    float v[4][4];
#pragma unroll
    for (int i = 0; i < 4; ++i)
#pragma unroll
        for (int j = 0; j < 4; ++j) v[i][j] = 0.f;

    for (int t = 0; t < T_; ++t) {
        const float* xt = x + (((size_t)t * B_ + b) * C_) * N_;
#pragma unroll
        for (int i = 0; i < 4; ++i) {
            int c = c0 + cl + 16 * i;
            float4 xv = *(const float4*)&xt[(size_t)c * N_ + n0 + nl];
            float xa[4] = {xv.x, xv.y, xv.z, xv.w};
#pragma unroll
            for (int j = 0; j < 4; ++j) {
                float vv = 0.5f * v[i][j] + xa[j];
                int sp = (vv >= 1.0f) ? 1 : 0;
                v[i][j] = sp ? 0.f : vv;
                Ls[nl + j][cl + 16 * i] = sp ? (f16)1.0f : (f16)0.0f;
            }
        }
        __syncthreads();
        {
            int r = tid >> 2, ch = (tid & 3) * 16;
            uint4 w0 = *(const uint4*)&Ls[r][ch];
            uint4 w1 = *(const uint4*)&Ls[r][ch + 8];
            f16* dst = s + (((size_t)t * B_ + b) * N_ + n0 + r) * (size_t)C_ + c0 + ch;
            *(uint4*)dst = w0;
            *(uint4*)(dst + 8) = w1;
        }
        __syncthreads();
    }
}

// ---------------------------------------------------------------------------
// Kernel 2: q/k GEMM + BN + in-kernel LIF.
// M-tile = gathered (4t x 32n) for one b => full 3072-block grid AND the
// whole t-recurrence inside the block (acc -> LDS P -> LIF -> spikes).
// Block 128m x 64d', 4 waves (wave 64m x 32d), BK=64, 2 f16 planes.
// d' in [0,768): <384 = q path, >=384 = k path.
// ---------------------------------------------------------------------------
__global__ __launch_bounds__(256)
void qk_gemm_lif_kernel(const f16* __restrict__ Wq, const f16* __restrict__ Wk,
                        const f16* __restrict__ S,
                        const float* __restrict__ qg, const float* __restrict__ qb,
                        const float* __restrict__ qm, const float* __restrict__ qv,
                        const float* __restrict__ kg, const float* __restrict__ kb,
                        const float* __restrict__ km, const float* __restrict__ kv,
                        f16* __restrict__ q_spk, f16* __restrict__ k_spk)
{
    __shared__ __align__(16) char smem[36864];
    f16 (*As)[72]      = reinterpret_cast<f16(*)[72]>(smem);            // [128][72]
    f16 (*Bs)[64][72]  = reinterpret_cast<f16(*)[64][72]>(smem + 18432);// [2][64][72]
    float (*P)[64]     = reinterpret_cast<float(*)[64]>(smem);          // [128][64] (reuse)

    const int tid  = threadIdx.x;
    const int lane = tid & 63;
    const int wave = tid >> 6;
    const int wm = wave & 1, wd = wave >> 1;
    const int l31 = lane & 31;
    const int lhi = lane >> 5;

    const int mb = blockIdx.x;            // 0..255
    const int b  = mb >> 3;
    const int n0 = (mb & 7) * 32;
    const int dp0 = blockIdx.y * 64;      // 0..704
    const int path = (dp0 >= C_) ? 1 : 0; // 0=q 1=k
    const int d0 = dp0 - path * C_;

    const f16* W = path ? Wk : Wq;
    const float* g_  = path ? kg : qg;
    const float* be_ = path ? kb : qb;
    const float* m_  = path ? km : qm;
    const float* va_ = path ? kv : qv;
    f16* spk = path ? k_spk : q_spk;

    const int dcol = d0 + wd * 32 + l31;
    const float inv = g_[dcol] / sqrtf(va_[dcol] + EPS_);
    const float add = be_[dcol] - m_[dcol] * inv;

    // staging map
    const int ar = tid >> 1;              // 0..127
    const int ah = (tid & 1) * 32;        // col half
    const int at = ar >> 5;               // t of this A row
    const int an = n0 + (ar & 31);        // n of this A row
    const f16* arow = S + (((size_t)at * B_ + b) * N_ + an) * (size_t)C_;

    const int bp = tid >> 7;              // plane
    const int brr = (tid >> 1) & 63;      // d row
    const int bh = (tid & 1) * 32;
    const f16* brow = W + (size_t)bp * NW_ + (size_t)(d0 + brr) * C_;

    f32x16 acc[2][2];                     // [msub][plane]
#pragma unroll
    for (int ms = 0; ms < 2; ++ms)
#pragma unroll
        for (int p = 0; p < 2; ++p)
#pragma unroll
            for (int r = 0; r < 16; ++r) acc[ms][p][r] = 0.f;

    for (int kc = 0; kc < C_; kc += 64) {
        __syncthreads();
        {
            const f16* ga = arow + kc + ah;
            *(uint4*)&As[ar][ah]      = *(const uint4*)(ga);
            *(uint4*)&As[ar][ah + 8]  = *(const uint4*)(ga + 8);
            *(uint4*)&As[ar][ah + 16] = *(const uint4*)(ga + 16);
            *(uint4*)&As[ar][ah + 24] = *(const uint4*)(ga + 24);
            const f16* gb = brow + kc + bh;
            *(uint4*)&Bs[bp][brr][bh]      = *(const uint4*)(gb);
            *(uint4*)&Bs[bp][brr][bh + 8]  = *(const uint4*)(gb + 8);
            *(uint4*)&Bs[bp][brr][bh + 16] = *(const uint4*)(gb + 16);
            *(uint4*)&Bs[bp][brr][bh + 24] = *(const uint4*)(gb + 24);
        }
        __syncthreads();
#pragma unroll
        for (int kk = 0; kk < 4; ++kk) {
            const int ko = kk * 16 + lhi * 8;
            f16x8 a0 = *(const f16x8*)&As[wm * 64 + l31][ko];
            f16x8 a1 = *(const f16x8*)&As[wm * 64 + 32 + l31][ko];
            f16x8 b0 = *(const f16x8*)&Bs[0][wd * 32 + l31][ko];
            f16x8 b1 = *(const f16x8*)&Bs[1][wd * 32 + l31][ko];
            acc[0][0] = __builtin_amdgcn_mfma_f32_32x32x16_f16(a0, b0, acc[0][0], 0, 0, 0);
            acc[1][0] = __builtin_amdgcn_mfma_f32_32x32x16_f16(a1, b0, acc[1][0], 0, 0, 0);
            acc[0][1] = __builtin_amdgcn_mfma_f32_32x32x16_f16(a0, b1, acc[0][1], 0, 0, 0);
            acc[1][1] = __builtin_amdgcn_mfma_f32_32x32x16_f16(a1, b1, acc[1][1], 0, 0, 0);
        }
    }

    // acc -> BN -> P (LDS, reuses As/Bs space)
    __syncthreads();
#pragma unroll
    for (int ms = 0; ms < 2; ++ms)
#pragma unroll
    for (int r = 0; r < 16; ++r) {
        int row = wm * 64 + ms * 32 + (r & 3) + 8 * (r >> 2) + 4 * lhi;
        float val = acc[ms][0][r] + acc[ms][1][r] * PSCALE_INV;
        P[row][wd * 32 + l31] = val * inv + add;
    }
    __syncthreads();

    // in-block LIF over t, write spikes
    {
        const int d = tid & 63;
        const int g = tid >> 6;
#pragma unroll
        for (int i = 0; i < 8; ++i) {
            const int nl = g + 4 * i;
            float v = 0.f;
#pragma unroll
            for (int t = 0; t < T_; ++t) {
                float p = P[t * 32 + nl][d];
                float vv = 0.5f * v + p;
                int sp = (vv >= 1.0f) ? 1 : 0;
                v = sp ? 0.f : vv;
                spk[(((size_t)t * B_ + b) * N_ + n0 + nl) * C_ + d0 + d] =
                    sp ? (f16)1.0f : (f16)0.0f;
            }
        }
    }
}

// ---------------------------------------------------------------------------
// Kernel 3: fused head-sum + decayed memory + attention LIF.
// ---------------------------------------------------------------------------
__global__ __launch_bounds__(256)
void head_attn_kernel(const f16* __restrict__ q_spk,
                      const float* __restrict__ alpha_p,
                      unsigned char* __restrict__ attn)
{
    int i = blockIdx.x * 256 + threadIdx.x;   // B*H*N = 65536
    int n = i & (N_ - 1);
    int h = (i >> 8) & (HEADS_ - 1);
    int b = i >> 11;
    const float alpha = alpha_p[0];
    const int stride = B_ * HEADS_ * N_;
    float M = 0.f, v = 0.f, Sprev = 0.f;
#pragma unroll
    for (int t = 0; t < T_; ++t) {
        const uint4* p = (const uint4*)(q_spk + (((size_t)(t * B_ + b) * N_) + n) * C_ + h * DH_);
        int cnt = 0;
#pragma unroll
        for (int j = 0; j < 6; ++j) {
            uint4 w = p[j];
            cnt += __popc(w.x & 0x04000400u) + __popc(w.y & 0x04000400u)
                 + __popc(w.z & 0x04000400u) + __popc(w.w & 0x04000400u);
        }
        float Sqt = (float)cnt;
        if (t == 0) M = Sqt;
        else        M = alpha * M + (1.f - alpha) * Sprev;
        float qsum = M + Sqt;
        float vv = 0.5f * v + qsum;
        unsigned char sp = (vv >= 0.5f) ? 1 : 0;
        v = sp ? 0.f : vv;
        attn[(size_t)t * stride + i] = sp;
        Sprev = Sqt;
    }
}

// ---------------------------------------------------------------------------
// Kernel 4: proj GEMM. M = (tb, n) flat; block 128m x 64d, 4 waves, BK=64,
// 2 planes. A = (attn & k_spk) masked at staging. Epilogue bias+BN -> out.
// ---------------------------------------------------------------------------
__global__ __launch_bounds__(256)
void proj_gemm_kernel(const f16* __restrict__ Wp,
                      const f16* __restrict__ K,
                      const unsigned char* __restrict__ attn,
                      const float* __restrict__ bias,
                      const float* __restrict__ gamma, const float* __restrict__ beta,
                      const float* __restrict__ mean,  const float* __restrict__ var,
                      float* __restrict__ out)
{
    __shared__ __align__(16) char smem[36864];
    f16 (*As)[72]     = reinterpret_cast<f16(*)[72]>(smem);
    f16 (*Bs)[64][72] = reinterpret_cast<f16(*)[64][72]>(smem + 18432);

    const int tid  = threadIdx.x;
    const int lane = tid & 63;
    const int wave = tid >> 6;
    const int wm = wave & 1, wd = wave >> 1;
    const int l31 = lane & 31;
    const int lhi = lane >> 5;

    const int mb = blockIdx.x;            // 0..255
    const int tb = mb >> 1;
    const int n0 = (mb & 1) * 128;
    const int d0 = blockIdx.y * 64;

    const int dcol = d0 + wd * 32 + l31;
    const float iv = gamma[dcol] / sqrtf(var[dcol] + EPS_);
    const float ad = beta[dcol] - mean[dcol] * iv + bias[dcol] * iv;

    const int ar = tid >> 1;
    const int ah = (tid & 1) * 32;
    const int an = n0 + ar;
    const f16* arow = K + ((size_t)tb * N_ + an) * (size_t)C_;
    const unsigned char* At = attn + (size_t)tb * HEADS_ * N_;

    const int bp = tid >> 7;
    const int brr = (tid >> 1) & 63;
    const int bh = (tid & 1) * 32;
    const f16* brow = Wp + (size_t)bp * NW_ + (size_t)(d0 + brr) * C_;

    f32x16 acc[2][2];
#pragma unroll
    for (int ms = 0; ms < 2; ++ms)
#pragma unroll
        for (int p = 0; p < 2; ++p)
#pragma unroll
            for (int r = 0; r < 16; ++r) acc[ms][p][r] = 0.f;

    for (int kc = 0; kc < C_; kc += 64) {
        __syncthreads();
        {
#pragma unroll
            for (int j = 0; j < 4; ++j) {
                int c = kc + ah + 8 * j;
                int h = c / DH_;
                unsigned char am = At[(size_t)h * N_ + an];
                uint4 val = am ? *(const uint4*)(arow + c) : make_uint4(0u, 0u, 0u, 0u);
                *(uint4*)&As[ar][ah + 8 * j] = val;
            }
            const f16* gb = brow + kc + bh;
            *(uint4*)&Bs[bp][brr][bh]      = *(const uint4*)(gb);
            *(uint4*)&Bs[bp][brr][bh + 8]  = *(const uint4*)(gb + 8);
            *(uint4*)&Bs[bp][brr][bh + 16] = *(const uint4*)(gb + 16);
            *(uint4*)&Bs[bp][brr][bh + 24] = *(const uint4*)(gb + 24);
        }
        __syncthreads();
#pragma unroll
        for (int kk = 0; kk < 4; ++kk) {
            const int ko = kk * 16 + lhi * 8;
            f16x8 a0 = *(const f16x8*)&As[wm * 64 + l31][ko];
            f16x8 a1 = *(const f16x8*)&As[wm * 64 + 32 + l31][ko];
            f16x8 b0 = *(const f16x8*)&Bs[0][wd * 32 + l31][ko];
            f16x8 b1 = *(const f16x8*)&Bs[1][wd * 32 + l31][ko];
            acc[0][0] = __builtin_amdgcn_mfma_f32_32x32x16_f16(a0, b0, acc[0][0], 0, 0, 0);
            acc[1][0] = __builtin_amdgcn_mfma_f32_32x32x16_f16(a1, b0, acc[1][0], 0, 0, 0);
            acc[0][1] = __builtin_amdgcn_mfma_f32_32x32x16_f16(a0, b1, acc[0][1], 0, 0, 0);
            acc[1][1] = __builtin_amdgcn_mfma_f32_32x32x16_f16(a1, b1, acc[1][1], 0, 0, 0);
        }
    }

    // epilogue: out[tb][dcol][n]
    float* obase = out + ((size_t)tb * C_ + dcol) * N_;
#pragma unroll
    for (int ms = 0; ms < 2; ++ms)
#pragma unroll
    for (int r = 0; r < 16; ++r) {
        int n = n0 + wm * 64 + ms * 32 + (r & 3) + 8 * (r >> 2) + 4 * lhi;
        float val = acc[ms][0][r] + acc[ms][1][r] * PSCALE_INV;
        obase[n] = val * iv + ad;
    }
}

// ---------------------------------------------------------------------------
extern "C" void kernel_launch(void* const* d_in, const int* in_sizes, int n_in,
                              void* d_out, int out_size, void* d_ws, size_t ws_size,
                              hipStream_t stream)
{
    const float* x       = (const float*)d_in[0];
    const float* q_w     = (const float*)d_in[1];
    const float* q_gamma = (const float*)d_in[2];
    const float* q_beta  = (const float*)d_in[3];
    const float* q_mean  = (const float*)d_in[4];
    const float* q_var   = (const float*)d_in[5];
    const float* k_w     = (const float*)d_in[6];
    const float* k_gamma = (const float*)d_in[7];
    const float* k_beta  = (const float*)d_in[8];
    const float* k_mean  = (const float*)d_in[9];
    const float* k_var   = (const float*)d_in[10];
    const float* proj_w  = (const float*)d_in[11];
    const float* proj_b  = (const float*)d_in[12];
    const float* p_gamma = (const float*)d_in[13];
    const float* p_beta  = (const float*)d_in[14];
    const float* p_mean  = (const float*)d_in[15];
    const float* p_var   = (const float*)d_in[16];
    const float* m_alpha = (const float*)d_in[17];

    float* out = (float*)d_out;

    const size_t SPK_BYTES = (size_t)T_ * B_ * N_ * C_ * sizeof(f16);
    const size_t W2_BYTES  = (size_t)2 * NW_ * sizeof(f16);

    unsigned char* ws = (unsigned char*)d_ws;
    size_t off = 0;
    auto carve = [&](size_t bytes) {
        off = (off + 255) & ~(size_t)255;
        void* p = ws + off;
        off += bytes;
        return p;
    };
    f16* s_f16  = (f16*)carve(SPK_BYTES);
    f16* q_spk  = (f16*)carve(SPK_BYTES);
    f16* k_spk  = (f16*)carve(SPK_BYTES);
    f16* Wq2    = (f16*)carve(W2_BYTES);
    f16* Wk2    = (f16*)carve(W2_BYTES);
    f16* Wp2    = (f16*)carve(W2_BYTES);
    unsigned char* attn = (unsigned char*)carve((size_t)T_ * B_ * HEADS_ * N_);

    // 1. input LIF + transpose (z<32) and weight split (z==32)
    dim3 pgrid1(4, 6, 33);
    prep_kernel<<<pgrid1, 256, 0, stream>>>(x, s_f16, q_w, k_w, proj_w, Wq2, Wk2, Wp2);

    // 2. q+k GEMM + BN + in-kernel LIF  (grid 256 x 12 = 3072 blocks)
    dim3 qkgrid(256, 12);
    qk_gemm_lif_kernel<<<qkgrid, 256, 0, stream>>>(Wq2, Wk2, s_f16,
                                                   q_gamma, q_beta, q_mean, q_var,
                                                   k_gamma, k_beta, k_mean, k_var,
                                                   q_spk, k_spk);

    // 3. fused head-sum + memory + attn LIF
    head_attn_kernel<<<(B_ * HEADS_ * N_) / 256, 256, 0, stream>>>(q_spk, m_alpha, attn);

    // 4. proj GEMM -> out  (grid 256 x 6 = 1536 blocks)
    dim3 pjgrid(256, 6);
    proj_gemm_kernel<<<pjgrid, 256, 0, stream>>>(Wp2, k_spk, attn, proj_b,
                                                 p_gamma, p_beta, p_mean, p_var, out);
}